// Round 1
// baseline (595.237 us; speedup 1.0000x reference)
//
#include <hip/hip_runtime.h>
#include <cmath>

// Problem dims
#define S 96
#define BB 32
#define II 64
#define H 256
#define ROWS (S*BB)         // 3072 independent (s,b) rows
#define R 16                // rows per block (all same b, s-chunk of 16)
#define NB (ROWS/R)         // 192 blocks
#define PADK 264            // LDS row stride in fp16 elems (+8 pad, 16B-aligned rows)

// ws float layout: fx | cx | weight-fragment region (ushort)
#define FX_OFF 0
#define CX_OFF (ROWS*H)
#define WREP_OFF (2*ROWS*H)   // byte-offset 6291456, 16B aligned

typedef __attribute__((ext_vector_type(8))) _Float16 f16x8;  // 8 fp16 = 4 VGPRs
typedef __attribute__((ext_vector_type(4))) float f32x4;
typedef unsigned short ushort_t;
typedef unsigned int uint_t;

__device__ inline ushort_t h2u(_Float16 h){ return __builtin_bit_cast(ushort_t, h); }

// ---------------- prep 1: input projections (fp32) ----------------
__global__ void proj_kernel(const float* __restrict__ x,
                            const float* __restrict__ W_fx, const float* __restrict__ b_fx,
                            const float* __restrict__ W_cx, const float* __restrict__ b_cx,
                            float* __restrict__ fx, float* __restrict__ cx)
{
    const int row = blockIdx.x;
    const int k = threadIdx.x;
    __shared__ float xs[II];
    if (k < II) xs[k] = x[row*II + k];
    __syncthreads();
    const float4* wf = reinterpret_cast<const float4*>(W_fx + k*II);
    const float4* wc = reinterpret_cast<const float4*>(W_cx + k*II);
    float af = 0.f, ac = 0.f;
#pragma unroll
    for (int i = 0; i < II/4; ++i) {
        float4 a = wf[i];
        float4 b = wc[i];
        const float* xp = &xs[i*4];
        af = fmaf(a.x, xp[0], fmaf(a.y, xp[1], fmaf(a.z, xp[2], fmaf(a.w, xp[3], af))));
        ac = fmaf(b.x, xp[0], fmaf(b.y, xp[1], fmaf(b.z, xp[2], fmaf(b.w, xp[3], ac))));
    }
    fx[row*H + k] = af + b_fx[k];
    cx[row*H + k] = ac + b_cx[k];
}

// ---------------- prep 2: weights → fp16 in MFMA B-fragment order --
// B[k][n] = W[n][k].  Fragment element (lane,j) of tile (nt,kt):
//   n = nt*16 + (lane&15), k = kt*32 + (lane>>4)*8 + j
// dst = ((nt*8 + kt)*64 + lane)*8 + j
// Region: Wf (fp16) | Wc (fp16), each 65536 ushort = 128 KB.
__global__ void repack_kernel(const float* __restrict__ Wf, const float* __restrict__ Wc,
                              ushort_t* __restrict__ wr)
{
    const int idx = blockIdx.x*256 + threadIdx.x;   // 0..65535
    const int n = idx >> 8, k = idx & 255;
    const int lane = (((k >> 3) & 3) << 4) | (n & 15);
    const int dst = ((((n >> 4)*8 + (k >> 5))*64) + lane)*8 + (k & 7);
    wr[dst]         = h2u((_Float16)Wf[n*H + k]);   // v_cvt_f16_f32, RNE
    wr[65536 + dst] = h2u((_Float16)Wc[n*H + k]);
}

// ---------------- main: MFMA recurrence, register-resident weights ----------------
// Block = (b, s-chunk): 16 rows, 512 threads = 8 waves, 192 blocks (one per CU).
// Wave w owns output cols [32w, 32w+32) of BOTH gates. All weights live in
// 128 VGPRs/wave for the whole recurrence — ZERO global weight traffic in the
// t-loop. Precision: fp16 2-term split on the h side ((aH+aL)·bH), fp16
// weights: z-error ~7e-5 abs (2^-12 weight mantissa, sqrt(256) accumulation).
// h double-buffered in LDS → single barrier per step.
__global__ __launch_bounds__(512, 2) void lstm_mfma_kernel(
    const float* __restrict__ fx, const float* __restrict__ cx,
    const ushort_t* __restrict__ wr,
    const float* __restrict__ b_fh, const float* __restrict__ b_ch,
    float* __restrict__ out)
{
    const int tid = threadIdx.x;
    const int w = tid >> 6, lane = tid & 63;
    const int m = lane & 15, q = lane >> 4;
    const int b = blockIdx.x & 31;
    const int s0 = (blockIdx.x >> 5) * R;

    __shared__ ushort_t hh[2][2][R][PADK];   // [buf][hi/lo][row][col]

    for (int i = tid; i < 2*2*R*PADK; i += 512) (&hh[0][0][0][0])[i] = 0;

    // persistent weight fragments: wF/wC[kt][n], 32 frags × 4 VGPR = 128 VGPRs
    f16x8 wF[8][2], wC[8][2];
    const int nt0 = w*2;
#pragma unroll
    for (int kt = 0; kt < 8; ++kt)
#pragma unroll
        for (int n = 0; n < 2; ++n) {
            const int fo = (((nt0 + n)*8 + kt)*64 + lane)*8;
            wF[kt][n] = *(const f16x8*)&wr[fo];
            wC[kt][n] = *(const f16x8*)&wr[65536 + fo];
        }

    int col[2]; col[0] = w*32 + m; col[1] = col[0] + 16;
    float bfh[2], bch[2], cxr[2][4], cst[2][4];
#pragma unroll
    for (int n = 0; n < 2; ++n) { bfh[n] = b_fh[col[n]]; bch[n] = b_ch[col[n]]; }
#pragma unroll
    for (int n = 0; n < 2; ++n)
#pragma unroll
        for (int reg = 0; reg < 4; ++reg) {
            const int rl = q*4 + reg;
            cxr[n][reg] = cx[((s0 + rl)*BB + b)*H + col[n]];
            cst[n][reg] = 0.f;
        }
    __syncthreads();

    float* hseq = out;
    float* hfin = out + (size_t)S*ROWS*H;
    float* cfin = hfin + (size_t)ROWS*H;

    int p = 0;
    for (int t = 0; t < S; ++t) {
        // issue fx loads early so L2 latency hides under the MFMA phase
        const float* fxt = fx + (t*BB + b)*H;
        float fxv[2] = { fxt[col[0]], fxt[col[1]] };

        f32x4 accF[2], accC[2];
#pragma unroll
        for (int n = 0; n < 2; ++n) {
            accF[n] = (f32x4){0.f, 0.f, 0.f, 0.f};
            accC[n] = (f32x4){0.f, 0.f, 0.f, 0.f};
        }

#pragma unroll
        for (int kt = 0; kt < 8; ++kt) {
            f16x8 aH = *(const f16x8*)&hh[p][0][m][kt*32 + q*8];
            f16x8 aL = *(const f16x8*)&hh[p][1][m][kt*32 + q*8];
#pragma unroll
            for (int n = 0; n < 2; ++n) {
                accF[n] = __builtin_amdgcn_mfma_f32_16x16x32_f16(aH, wF[kt][n], accF[n], 0, 0, 0);
                accF[n] = __builtin_amdgcn_mfma_f32_16x16x32_f16(aL, wF[kt][n], accF[n], 0, 0, 0);
                accC[n] = __builtin_amdgcn_mfma_f32_16x16x32_f16(aH, wC[kt][n], accC[n], 0, 0, 0);
                accC[n] = __builtin_amdgcn_mfma_f32_16x16x32_f16(aL, wC[kt][n], accC[n], 0, 0, 0);
            }
        }

        // elementwise update; writes go to the OTHER h buffer (no barrier needed
        // before: between two step-barriers every wave reads buf[p], writes buf[p^1])
#pragma unroll
        for (int n = 0; n < 2; ++n)
#pragma unroll
            for (int reg = 0; reg < 4; ++reg) {
                const int rl = q*4 + reg;
                const float zf = accF[n][reg] + fxv[n] + bfh[n];
                const float g = 1.f / (1.f + __expf(-zf));
                const float zc = accC[n][reg] + cxr[n][reg] + bch[n];
                const float cand = 1.f - 2.f / (1.f + __expf(2.f*zc));   // tanh
                const float cn = g * (cst[n][reg] + cand);
                cst[n][reg] = cn;
                const float hn = g * (1.f - 2.f / (1.f + __expf(2.f*cn)));
                hseq[(((size_t)t*S + (s0 + rl))*BB + b)*H + col[n]] = hn;
                const _Float16 hi16 = (_Float16)hn;
                const _Float16 lo16 = (_Float16)(hn - (float)hi16);
                hh[p^1][0][rl][col[n]] = h2u(hi16);
                hh[p^1][1][rl][col[n]] = h2u(lo16);
                if (t == S-1) {
                    hfin[((s0 + rl)*BB + b)*H + col[n]] = hn;
                    cfin[((s0 + rl)*BB + b)*H + col[n]] = cn;
                }
            }
        __syncthreads();   // h writes visible before next step's fragment reads
        p ^= 1;
    }
}

extern "C" void kernel_launch(void* const* d_in, const int* in_sizes, int n_in,
                              void* d_out, int out_size, void* d_ws, size_t ws_size,
                              hipStream_t stream)
{
    const float* x    = (const float*)d_in[0];
    const float* W_fx = (const float*)d_in[1];
    const float* b_fx = (const float*)d_in[2];
    const float* W_fh = (const float*)d_in[3];
    const float* b_fh = (const float*)d_in[4];
    const float* W_cx = (const float*)d_in[5];
    const float* b_cx = (const float*)d_in[6];
    const float* W_ch = (const float*)d_in[7];
    const float* b_ch = (const float*)d_in[8];
    float* out = (float*)d_out;
    float* ws  = (float*)d_ws;

    float* fx = ws + FX_OFF;
    float* cx = ws + CX_OFF;
    ushort_t* wrp = (ushort_t*)(ws + WREP_OFF);

    hipLaunchKernelGGL(proj_kernel, dim3(ROWS), dim3(H), 0, stream,
                       x, W_fx, b_fx, W_cx, b_cx, fx, cx);
    hipLaunchKernelGGL(repack_kernel, dim3(H*H/256), dim3(256), 0, stream,
                       W_fh, W_ch, wrp);
    hipLaunchKernelGGL(lstm_mfma_kernel, dim3(NB), dim3(512), 0, stream,
                       fx, cx, wrp, b_fh, b_ch, out);
}

// Round 2
// 575.741 us; speedup vs baseline: 1.0339x; 1.0339x over previous
//
#include <hip/hip_runtime.h>
#include <cmath>

// Problem dims
#define S 96
#define BB 32
#define II 64
#define H 256
#define ROWS (S*BB)         // 3072 independent (s,b) rows
#define R 16                // rows per block (all same b, s-chunk of 16)
#define NB (ROWS/R)         // 192 blocks
#define NT 1024             // 16 waves per block, 4 per SIMD
#define PADK 264            // LDS row stride in fp16 elems (+8 pad, 16B-aligned rows)

// ws float layout: fx | cx | weight-fragment region (ushort)
#define FX_OFF 0
#define CX_OFF (ROWS*H)
#define WREP_OFF (2*ROWS*H)   // byte-offset 6291456, 16B aligned

typedef __attribute__((ext_vector_type(8))) _Float16 f16x8;  // 8 fp16 = 4 VGPRs
typedef __attribute__((ext_vector_type(4))) float f32x4;
typedef unsigned short ushort_t;

__device__ inline ushort_t h2u(_Float16 h){ return __builtin_bit_cast(ushort_t, h); }

// ---------------- prep 1: input projections (fp32), recurrent biases folded in --
__global__ void proj_kernel(const float* __restrict__ x,
                            const float* __restrict__ W_fx, const float* __restrict__ b_fx,
                            const float* __restrict__ W_cx, const float* __restrict__ b_cx,
                            const float* __restrict__ b_fh, const float* __restrict__ b_ch,
                            float* __restrict__ fx, float* __restrict__ cx)
{
    const int row = blockIdx.x;
    const int k = threadIdx.x;
    __shared__ float xs[II];
    if (k < II) xs[k] = x[row*II + k];
    __syncthreads();
    const float4* wf = reinterpret_cast<const float4*>(W_fx + k*II);
    const float4* wc = reinterpret_cast<const float4*>(W_cx + k*II);
    float af = 0.f, ac = 0.f;
#pragma unroll
    for (int i = 0; i < II/4; ++i) {
        float4 a = wf[i];
        float4 b = wc[i];
        const float* xp = &xs[i*4];
        af = fmaf(a.x, xp[0], fmaf(a.y, xp[1], fmaf(a.z, xp[2], fmaf(a.w, xp[3], af))));
        ac = fmaf(b.x, xp[0], fmaf(b.y, xp[1], fmaf(b.z, xp[2], fmaf(b.w, xp[3], ac))));
    }
    fx[row*H + k] = af + b_fx[k] + b_fh[k];   // fold recurrent bias: zf = accF + fx
    cx[row*H + k] = ac + b_cx[k] + b_ch[k];   // fold recurrent bias: zc = accC + cx
}

// ---------------- prep 2: weights → fp16 in MFMA B-fragment order --
// B[k][n] = W[n][k].  Fragment element (lane,j) of tile (nt,kt):
//   n = nt*16 + (lane&15), k = kt*32 + (lane>>4)*8 + j
// dst = ((nt*8 + kt)*64 + lane)*8 + j
// Region: Wf (fp16) | Wc (fp16), each 65536 ushort = 128 KB.
__global__ void repack_kernel(const float* __restrict__ Wf, const float* __restrict__ Wc,
                              ushort_t* __restrict__ wr)
{
    const int idx = blockIdx.x*256 + threadIdx.x;   // 0..65535
    const int n = idx >> 8, k = idx & 255;
    const int lane = (((k >> 3) & 3) << 4) | (n & 15);
    const int dst = ((((n >> 4)*8 + (k >> 5))*64) + lane)*8 + (k & 7);
    wr[dst]         = h2u((_Float16)Wf[n*H + k]);   // v_cvt_f16_f32, RNE
    wr[65536 + dst] = h2u((_Float16)Wc[n*H + k]);
}

// ---------------- main: MFMA recurrence, register-resident weights ----------------
// Block = (b, s-chunk): 16 rows, 1024 threads = 16 waves (4/SIMD), 192 blocks.
// Wave w owns output cols [16w, 16w+16) of BOTH gates; weights for that tile are
// 64 VGPRs, register-resident for the whole recurrence. Per step: one raw
// s_barrier with lgkmcnt(0) ONLY — no vmcnt(0) store drain (hseq stores are
// block-private, they retire lazily under the next step's MFMA phase). fx for
// step t+1 is prefetched BEFORE step t's stores so its in-order vmcnt wait is
// not queued behind them.
__global__ __launch_bounds__(NT, 4) void lstm_mfma_kernel(
    const float* __restrict__ fx, const float* __restrict__ cx,
    const ushort_t* __restrict__ wr,
    float* __restrict__ out)
{
    const int tid = threadIdx.x;
    const int w = tid >> 6, lane = tid & 63;
    const int m = lane & 15, q = lane >> 4;
    const int b = blockIdx.x & 31;
    const int s0 = (blockIdx.x >> 5) * R;
    const int col = w*16 + m;

    __shared__ ushort_t hh[2][2][R][PADK];   // [buf][hi/lo][row][col]

    for (int i = tid; i < 2*2*R*PADK; i += NT) (&hh[0][0][0][0])[i] = 0;

    // persistent weight fragments: 16 frags × 4 VGPR = 64 VGPRs
    f16x8 wF[8], wC[8];
#pragma unroll
    for (int kt = 0; kt < 8; ++kt) {
        const int fo = ((w*8 + kt)*64 + lane)*8;
        wF[kt] = *(const f16x8*)&wr[fo];
        wC[kt] = *(const f16x8*)&wr[65536 + fo];
    }

    float cxr[4], cst[4];
#pragma unroll
    for (int reg = 0; reg < 4; ++reg) {
        cxr[reg] = cx[((s0 + q*4 + reg)*BB + b)*H + col];
        cst[reg] = 0.f;
    }

    float* hseq = out;
    float* hfin = out + (size_t)S*ROWS*H;
    float* cfin = hfin + (size_t)ROWS*H;

    const float* fxp = fx + b*H + col;
    float* op[4];
#pragma unroll
    for (int reg = 0; reg < 4; ++reg)
        op[reg] = hseq + ((size_t)(s0 + q*4 + reg)*BB + b)*H + col;

    __syncthreads();

    float fxv = fxp[0];

#define LSTM_STEP(P, IS_LAST) do { \
    f32x4 accF = (f32x4){0.f,0.f,0.f,0.f}; \
    f32x4 accC = (f32x4){0.f,0.f,0.f,0.f}; \
    _Pragma("unroll") \
    for (int kt = 0; kt < 8; ++kt) { \
        f16x8 aH = *(const f16x8*)&hh[P][0][m][kt*32 + q*8]; \
        f16x8 aL = *(const f16x8*)&hh[P][1][m][kt*32 + q*8]; \
        accF = __builtin_amdgcn_mfma_f32_16x16x32_f16(aH, wF[kt], accF, 0, 0, 0); \
        accF = __builtin_amdgcn_mfma_f32_16x16x32_f16(aL, wF[kt], accF, 0, 0, 0); \
        accC = __builtin_amdgcn_mfma_f32_16x16x32_f16(aH, wC[kt], accC, 0, 0, 0); \
        accC = __builtin_amdgcn_mfma_f32_16x16x32_f16(aL, wC[kt], accC, 0, 0, 0); \
    } \
    const float fxn = fxp[BB*H];   /* prefetch t+1 BEFORE this step's stores */ \
    fxp += BB*H; \
    _Pragma("unroll") \
    for (int reg = 0; reg < 4; ++reg) { \
        const float zf = accF[reg] + fxv; \
        const float g  = 1.f/(1.f + __expf(-zf)); \
        const float zc = accC[reg] + cxr[reg]; \
        const float cand = 1.f - 2.f/(1.f + __expf(2.f*zc));   /* tanh */ \
        const float cn = g*(cst[reg] + cand); \
        cst[reg] = cn; \
        const float hn = g*(1.f - 2.f/(1.f + __expf(2.f*cn))); \
        *op[reg] = hn; op[reg] += (size_t)S*BB*H; \
        const _Float16 hi = (_Float16)hn; \
        const _Float16 lo = (_Float16)(hn - (float)hi); \
        hh[(P)^1][0][q*4 + reg][col] = h2u(hi); \
        hh[(P)^1][1][q*4 + reg][col] = h2u(lo); \
        if (IS_LAST) { \
            const size_t ro = ((size_t)(s0 + q*4 + reg)*BB + b)*H + col; \
            hfin[ro] = hn; cfin[ro] = cn; \
        } \
    } \
    fxv = fxn; \
    asm volatile("s_waitcnt lgkmcnt(0)" ::: "memory"); \
    __builtin_amdgcn_s_barrier(); \
    asm volatile("" ::: "memory"); \
} while (0)

    for (int t = 0; t < S-2; t += 2) {
        LSTM_STEP(0, 0);
        LSTM_STEP(1, 0);
    }
    LSTM_STEP(0, 0);
    LSTM_STEP(1, 1);

#undef LSTM_STEP
}

extern "C" void kernel_launch(void* const* d_in, const int* in_sizes, int n_in,
                              void* d_out, int out_size, void* d_ws, size_t ws_size,
                              hipStream_t stream)
{
    const float* x    = (const float*)d_in[0];
    const float* W_fx = (const float*)d_in[1];
    const float* b_fx = (const float*)d_in[2];
    const float* W_fh = (const float*)d_in[3];
    const float* b_fh = (const float*)d_in[4];
    const float* W_cx = (const float*)d_in[5];
    const float* b_cx = (const float*)d_in[6];
    const float* W_ch = (const float*)d_in[7];
    const float* b_ch = (const float*)d_in[8];
    float* out = (float*)d_out;
    float* ws  = (float*)d_ws;

    float* fx = ws + FX_OFF;
    float* cx = ws + CX_OFF;
    ushort_t* wrp = (ushort_t*)(ws + WREP_OFF);

    hipLaunchKernelGGL(proj_kernel, dim3(ROWS), dim3(H), 0, stream,
                       x, W_fx, b_fx, W_cx, b_cx, b_fh, b_ch, fx, cx);
    hipLaunchKernelGGL(repack_kernel, dim3(H*H/256), dim3(256), 0, stream,
                       W_fh, W_ch, wrp);
    hipLaunchKernelGGL(lstm_mfma_kernel, dim3(NB), dim3(NT), 0, stream,
                       fx, cx, wrp, out);
}